// Round 1
// 1813.525 us; speedup vs baseline: 1.4723x; 1.4723x over previous
//
#include <hip/hip_runtime.h>

#define NN 100000
#define NE 1600000
#define DD 128
#define SCAN_CHUNK 1024
#define NBLK ((NN + SCAN_CHUNK - 1) / SCAN_CHUNK)   // 98

using u16 = unsigned short;
using u32 = unsigned int;
using u64 = unsigned long long;

typedef __bf16 bf16x8 __attribute__((ext_vector_type(8)));
typedef float  f32x4  __attribute__((ext_vector_type(4)));

__device__ __forceinline__ float bf2f(u16 h){ return __uint_as_float(((u32)h) << 16); }
__device__ __forceinline__ u16 f2bf(float f){
  u32 u = __float_as_uint(f);
  u += 0x7FFFu + ((u >> 16) & 1u);   // round-to-nearest-even
  return (u16)(u >> 16);
}
__device__ __forceinline__ int ld_idx(const int* __restrict__ p, long long k, int w64){
  return w64 ? p[2*k] : p[k];
}
__device__ __forceinline__ float ldf(const void* __restrict__ p, long long k, int f32){
  return f32 ? ((const float*)p)[k] : bf2f(((const u16*)p)[k]);
}

// flags[0] = edge_index is int64 layout; flags[1] = float tensors are fp32
__global__ void detect_kernel(const int* __restrict__ ei, const u16* __restrict__ xw,
                              int* __restrict__ flags){
  if (threadIdx.x == 0 && blockIdx.x == 0){
    int all0 = 1;
    for (int k = 1; k < 256; k += 2) all0 &= (ei[k] == 0);
    flags[0] = all0;
    int cnt = 0;
    for (int i = 0; i < 128; ++i){
      u16 w = xw[2*i];
      int e = (w >> 7) & 0xFF;
      cnt += (e >= 100 && e <= 130);
    }
    flags[1] = (cnt < 64);
  }
}

// convert all 5 weight matrices (lin_w, conv_w[0..3]) to bf16 [d][k] row-major
__global__ __launch_bounds__(256) void prep_w_kernel(const void* __restrict__ lin_w,
    const void* __restrict__ conv_w, const int* __restrict__ flags, u16* __restrict__ wbf){
  int i = blockIdx.x*256 + threadIdx.x;
  if (i >= 5*DD*DD) return;
  int f32 = flags[1];
  float v = (i < DD*DD) ? ldf(lin_w, i, f32) : ldf(conv_w, i - DD*DD, f32);
  wbf[i] = f2bf(v);
}

// single u64 atomic per edge: count at bit 40, weight as 24-bit fixed point in low bits
__global__ __launch_bounds__(256) void hist_kernel(const void* __restrict__ ea, long long ea_off,
    const int* __restrict__ ei, long long col_off,
    const int* __restrict__ flags, u64* __restrict__ pk){
  int e = blockIdx.x*256 + threadIdx.x;
  if (e >= NE) return;
  int col = ld_idx(ei, col_off + e, flags[0]);
  float w = ldf(ea, ea_off + e, flags[1]);
  u64 v = (1ull << 40) | (u64)(w * 16777216.0f);
  atomicAdd(pk + col, v);
}

__global__ __launch_bounds__(256) void dinv_kernel(const u64* __restrict__ pk,
    float* __restrict__ dinv, int* __restrict__ cnt){
  int n = blockIdx.x*256 + threadIdx.x;
  if (n >= NN) return;
  u64 p = pk[n];
  cnt[n] = (int)(p >> 40);
  float d = (float)(p & ((1ull << 40) - 1)) * (1.0f/16777216.0f);
  dinv[n] = (d > 0.f) ? rsqrtf(d) : 0.f;
}

// ---- exclusive scan of cnt[NN] into base[NN]  (3 kernels) ----
__global__ __launch_bounds__(256) void scan_block_kernel(const int* __restrict__ cnt,
    int* __restrict__ base, int* __restrict__ bsums){
  __shared__ int sm[256];
  int b = blockIdx.x, t = threadIdx.x;
  int i0 = b*SCAN_CHUNK + t*4;
  int v[4];
  #pragma unroll
  for (int j = 0; j < 4; ++j) v[j] = (i0 + j < NN) ? cnt[i0 + j] : 0;
  int s = v[0] + v[1] + v[2] + v[3];
  sm[t] = s;
  __syncthreads();
  for (int off = 1; off < 256; off <<= 1){
    int add = (t >= off) ? sm[t - off] : 0;
    __syncthreads();
    sm[t] += add;
    __syncthreads();
  }
  int run = sm[t] - s;          // exclusive prefix of this thread
  if (t == 255) bsums[b] = sm[255];
  #pragma unroll
  for (int j = 0; j < 4; ++j){
    if (i0 + j < NN) base[i0 + j] = run;
    run += v[j];
  }
}

__global__ void scan_sums_kernel(int* __restrict__ bsums, int nb){
  __shared__ int sm[256];
  int t = threadIdx.x;
  int v = (t < nb) ? bsums[t] : 0;
  sm[t] = v;
  __syncthreads();
  for (int off = 1; off < 256; off <<= 1){
    int add = (t >= off) ? sm[t - off] : 0;
    __syncthreads();
    sm[t] += add;
    __syncthreads();
  }
  if (t < nb) bsums[t] = sm[t] - v;   // exclusive
}

__global__ __launch_bounds__(256) void scan_add_kernel(int* __restrict__ base,
    const int* __restrict__ bsums, int* __restrict__ cursor){
  int i = blockIdx.x*256 + threadIdx.x;
  if (i >= NN) return;
  int b = base[i] + bsums[i / SCAN_CHUNK];
  base[i] = b;
  cursor[i] = b;
}

// rc[pos] = {row, coef} at pos=cursor[col]++  (single 8B store)
__global__ __launch_bounds__(256) void fill_kernel(const void* __restrict__ ea, long long ea_off,
    const int* __restrict__ ei, long long row_off, long long col_off,
    const float* __restrict__ dinv, const int* __restrict__ flags,
    int* __restrict__ cursor, int2* __restrict__ rc){
  int e = blockIdx.x*256 + threadIdx.x;
  if (e >= NE) return;
  int w64 = flags[0];
  int row = ld_idx(ei, row_off + e, w64);
  int col = ld_idx(ei, col_off + e, w64);
  float w = ldf(ea, ea_off + e, flags[1]);
  int pos = atomicAdd(cursor + col, 1);
  rc[pos] = make_int2(row, __float_as_int(dinv[row] * w * dinv[col]));
}

// one wave per node: agg[n] = sum_j coef[j] * h[rows[j]]
__global__ __launch_bounds__(256) void aggregate_kernel(
    const void* __restrict__ hbase, long long h_off,
    const int2* __restrict__ rc,
    const int* __restrict__ base, const int* __restrict__ cnt,
    const int* __restrict__ flags, void* __restrict__ agg, int agg_f32){
  int wid = (int)(((long long)blockIdx.x*256 + threadIdx.x) >> 6);
  int l = threadIdx.x & 63;
  if (wid >= NN) return;
  int f32 = flags[1];
  int s = base[wid], e = s + cnt[wid];
  float ax = 0.f, ay = 0.f;
  if (f32){
    const float2* hp = (const float2*)((const float*)hbase + h_off);
    for (int j = s; j < e; ++j){
      int2 v = rc[j];
      float c = __int_as_float(v.y);
      float2 hv = hp[(long long)v.x*64 + l];
      ax += c*hv.x; ay += c*hv.y;
    }
  } else {
    const u32* hp = (const u32*)((const u16*)hbase + h_off);
    for (int j = s; j < e; ++j){
      int2 v = rc[j];
      float c = __int_as_float(v.y);
      u32 hv = hp[(long long)v.x*64 + l];
      ax += c*bf2f((u16)(hv & 0xFFFF));
      ay += c*bf2f((u16)(hv >> 16));
    }
  }
  if (agg_f32) ((float2*)agg)[(long long)wid*64 + l] = make_float2(ax, ay);
  else         ((u32*)agg)[(long long)wid*64 + l] = ((u32)f2bf(ay) << 16) | (u32)f2bf(ax);
}

// out = relu(in @ W^T + bias) via MFMA bf16 with hi/lo split of fp32 inputs.
// in_mode: 0=bf16, 1=f32, 2=follow flags[1].  wbf = bf16 W [128][128] row-major [d][k].
// Block: 256 thr = 4 waves, 64 rows/block (16 rows/wave), full 128 cols (8 col-tiles).
__global__ __launch_bounds__(256) void gemm_mfma_kernel(
    const void* __restrict__ in, int in_mode,
    const u16* __restrict__ wbf,
    const void* __restrict__ bias, long long b_off,
    const int* __restrict__ flags,
    void* __restrict__ outb, long long out_off){
  __shared__ u16 ah[64*DD];   // bf16 hi, XOR-swizzled
  __shared__ u16 al[64*DD];   // bf16 lo (residual), XOR-swizzled
  int t = threadIdx.x;
  int f32 = flags[1];
  int inf32 = (in_mode == 2) ? f32 : in_mode;
  long long rowbase = (long long)blockIdx.x * 64;

  // stage 64x128 input rows -> hi/lo bf16 in LDS (swizzle: u16idx ^= (row&7)<<3)
  #pragma unroll
  for (int it = 0; it < 8; ++it){
    int i = (it*256 + t) * 4;           // element index, multiple of 4
    int r = i >> 7, c = i & 127;
    long long gr = rowbase + r;
    float v0, v1, v2, v3;
    if (gr < NN){
      if (inf32){
        const float4 f = *(const float4*)((const float*)in + gr*DD + c);
        v0 = f.x; v1 = f.y; v2 = f.z; v3 = f.w;
      } else {
        const ushort4 u = *(const ushort4*)((const u16*)in + gr*DD + c);
        v0 = bf2f(u.x); v1 = bf2f(u.y); v2 = bf2f(u.z); v3 = bf2f(u.w);
      }
    } else { v0 = v1 = v2 = v3 = 0.f; }
    u16 h0 = f2bf(v0), h1 = f2bf(v1), h2 = f2bf(v2), h3 = f2bf(v3);
    u16 l0 = f2bf(v0 - bf2f(h0)), l1 = f2bf(v1 - bf2f(h1));
    u16 l2 = f2bf(v2 - bf2f(h2)), l3 = f2bf(v3 - bf2f(h3));
    int idx = (r*DD + c) ^ ((r & 7) << 3);
    *(ushort4*)&ah[idx] = make_ushort4(h0, h1, h2, h3);
    *(ushort4*)&al[idx] = make_ushort4(l0, l1, l2, l3);
  }
  __syncthreads();

  const int w  = t >> 6, l = t & 63;
  const int lr = l & 15, lg = l >> 4;
  const int arow = w*16 + lr;
  f32x4 acc[8];
  #pragma unroll
  for (int j = 0; j < 8; ++j) acc[j] = (f32x4){0.f, 0.f, 0.f, 0.f};

  #pragma unroll
  for (int s = 0; s < 4; ++s){
    const int kb = s*32 + lg*8;
    const int aidx = (arow*DD + kb) ^ ((arow & 7) << 3);
    bf16x8 afh = *(const bf16x8*)&ah[aidx];
    bf16x8 afl = *(const bf16x8*)&al[aidx];
    #pragma unroll
    for (int tt = 0; tt < 8; ++tt){
      bf16x8 bfr = *(const bf16x8*)&wbf[(tt*16 + lr)*DD + kb];
      acc[tt] = __builtin_amdgcn_mfma_f32_16x16x32_bf16(afh, bfr, acc[tt], 0, 0, 0);
      acc[tt] = __builtin_amdgcn_mfma_f32_16x16x32_bf16(afl, bfr, acc[tt], 0, 0, 0);
    }
  }

  // C/D layout: col = lane&15, row = (lane>>4)*4 + reg
  const long long gn0 = rowbase + w*16 + lg*4;
  #pragma unroll
  for (int tt = 0; tt < 8; ++tt){
    const int d = tt*16 + lr;
    const float bv = ldf(bias, b_off + d, f32);
    #pragma unroll
    for (int q = 0; q < 4; ++q){
      long long gn = gn0 + q;
      if (gn < NN){
        float vv = fmaxf(acc[tt][q] + bv, 0.f);
        long long gi = out_off + gn*DD + d;
        if (f32) ((float*)outb)[gi] = vv;
        else     ((u16*)outb)[gi] = f2bf(vv);
      }
    }
  }
}

extern "C" void kernel_launch(void* const* d_in, const int* in_sizes, int n_in,
                              void* d_out, int out_size, void* d_ws, size_t ws_size,
                              hipStream_t stream){
  const void* x      = d_in[0];
  const int*  ei     = (const int*)d_in[1];
  const void* ea     = d_in[2];
  const void* lin_w  = d_in[3];
  const void* lin_b  = d_in[4];
  const void* conv_w = d_in[5];
  const void* conv_b = d_in[6];
  void* out = d_out;

  char* ws = (char*)d_ws;
  size_t o = 0;
  auto alloc = [&](size_t bytes){ void* p = ws + o; o = (o + bytes + 255) & ~(size_t)255; return p; };
  int*   flags  = (int*)  alloc(256);
  u64*   pk     = (u64*)  alloc((size_t)NN*8);   // packed {cnt<<40 | fixpt deg}
  float* dinv   = (float*)alloc((size_t)NN*4);
  int*   cnt    = (int*)  alloc((size_t)NN*4);
  int*   base   = (int*)  alloc((size_t)NN*4);
  int*   cursor = (int*)  alloc((size_t)NN*4);
  int*   bsums  = (int*)  alloc(4096);
  int2*  rc     = (int2*) alloc((size_t)NE*8);
  u16*   wbf    = (u16*)  alloc((size_t)5*DD*DD*2);
  size_t fixed = o;
  int agg_f32 = (ws_size >= fixed + (size_t)NN*DD*4) ? 1 : 0;
  void* agg = alloc((size_t)NN*DD*(agg_f32 ? 4 : 2));

  detect_kernel<<<1, 64, 0, stream>>>(ei, (const u16*)x, flags);
  prep_w_kernel<<<(5*DD*DD + 255)/256, 256, 0, stream>>>(lin_w, conv_w, flags, wbf);

  // layer 0: out[0] = relu(x @ lin_w.T + lin_b)
  gemm_mfma_kernel<<<(NN+63)/64, 256, 0, stream>>>(x, 2, wbf, lin_b, 0, flags, out, 0);

  for (int i = 0; i < 4; ++i){
    long long h_off   = (long long)i*NN*DD;
    long long o_off   = (long long)(i+1)*NN*DD;
    long long row_off = ((long long)i*2 + 0)*NE;
    long long col_off = ((long long)i*2 + 1)*NE;
    long long ea_off  = (long long)i*NE;

    hipMemsetAsync(pk, 0, (size_t)NN*8, stream);
    hist_kernel<<<(NE+255)/256, 256, 0, stream>>>(ea, ea_off, ei, col_off, flags, pk);
    dinv_kernel<<<(NN+255)/256, 256, 0, stream>>>(pk, dinv, cnt);

    scan_block_kernel<<<NBLK, 256, 0, stream>>>(cnt, base, bsums);
    scan_sums_kernel<<<1, 256, 0, stream>>>(bsums, NBLK);
    scan_add_kernel<<<(NN+255)/256, 256, 0, stream>>>(base, bsums, cursor);

    fill_kernel<<<(NE+255)/256, 256, 0, stream>>>(ea, ea_off, ei, row_off, col_off,
                                                  dinv, flags, cursor, rc);

    aggregate_kernel<<<(NN*64 + 255)/256, 256, 0, stream>>>(out, h_off, rc,
                                                            base, cnt, flags, agg, agg_f32);

    gemm_mfma_kernel<<<(NN+63)/64, 256, 0, stream>>>(agg, agg_f32 ? 1 : 0,
                                                     wbf + (size_t)(1+i)*DD*DD,
                                                     conv_b, (long long)i*DD, flags, out, o_off);
  }
}

// Round 2
// 1624.305 us; speedup vs baseline: 1.6438x; 1.1165x over previous
//
#include <hip/hip_runtime.h>

#define NN 100000
#define NE 1600000
#define DD 128
#define SCAN_CHUNK 1024
#define NBLK ((NN + SCAN_CHUNK - 1) / SCAN_CHUNK)   // 98

using u16 = unsigned short;
using u32 = unsigned int;
using u64 = unsigned long long;

typedef __bf16 bf16x8 __attribute__((ext_vector_type(8)));
typedef float  f32x4  __attribute__((ext_vector_type(4)));

__device__ __forceinline__ float bf2f(u16 h){ return __uint_as_float(((u32)h) << 16); }
__device__ __forceinline__ u16 f2bf(float f){
  u32 u = __float_as_uint(f);
  u += 0x7FFFu + ((u >> 16) & 1u);   // round-to-nearest-even
  return (u16)(u >> 16);
}
__device__ __forceinline__ int ld_idx(const int* __restrict__ p, long long k, int w64){
  return w64 ? p[2*k] : p[k];
}
__device__ __forceinline__ float ldf(const void* __restrict__ p, long long k, int f32){
  return f32 ? ((const float*)p)[k] : bf2f(((const u16*)p)[k]);
}

// flags[0] = edge_index is int64 layout; flags[1] = float tensors are fp32
__global__ void detect_kernel(const int* __restrict__ ei, const u16* __restrict__ xw,
                              int* __restrict__ flags){
  if (threadIdx.x == 0 && blockIdx.x == 0){
    int all0 = 1;
    for (int k = 1; k < 256; k += 2) all0 &= (ei[k] == 0);
    flags[0] = all0;
    int cnt = 0;
    for (int i = 0; i < 128; ++i){
      u16 w = xw[2*i];
      int e = (w >> 7) & 0xFF;
      cnt += (e >= 100 && e <= 130);
    }
    flags[1] = (cnt < 64);
  }
}

// convert all 5 weight matrices (lin_w, conv_w[0..3]) to bf16 [d][k] row-major
__global__ __launch_bounds__(256) void prep_w_kernel(const void* __restrict__ lin_w,
    const void* __restrict__ conv_w, const int* __restrict__ flags, u16* __restrict__ wbf){
  int i = blockIdx.x*256 + threadIdx.x;
  if (i >= 5*DD*DD) return;
  int f32 = flags[1];
  float v = (i < DD*DD) ? ldf(lin_w, i, f32) : ldf(conv_w, i - DD*DD, f32);
  wbf[i] = f2bf(v);
}

// single u64 atomic per edge: count at bit 40, weight as 24-bit fixed point in low bits
__global__ __launch_bounds__(256) void hist_kernel(const void* __restrict__ ea, long long ea_off,
    const int* __restrict__ ei, long long col_off,
    const int* __restrict__ flags, u64* __restrict__ pk){
  int e = blockIdx.x*256 + threadIdx.x;
  if (e >= NE) return;
  int col = ld_idx(ei, col_off + e, flags[0]);
  float w = ldf(ea, ea_off + e, flags[1]);
  u64 v = (1ull << 40) | (u64)(w * 16777216.0f);
  atomicAdd(pk + col, v);
}

__global__ __launch_bounds__(256) void dinv_kernel(const u64* __restrict__ pk,
    float* __restrict__ dinv, int* __restrict__ cnt){
  int n = blockIdx.x*256 + threadIdx.x;
  if (n >= NN) return;
  u64 p = pk[n];
  cnt[n] = (int)(p >> 40);
  float d = (float)(p & ((1ull << 40) - 1)) * (1.0f/16777216.0f);
  dinv[n] = (d > 0.f) ? rsqrtf(d) : 0.f;
}

// ---- exclusive scan of cnt[NN] into base[NN]  (3 kernels) ----
__global__ __launch_bounds__(256) void scan_block_kernel(const int* __restrict__ cnt,
    int* __restrict__ base, int* __restrict__ bsums){
  __shared__ int sm[256];
  int b = blockIdx.x, t = threadIdx.x;
  int i0 = b*SCAN_CHUNK + t*4;
  int v[4];
  #pragma unroll
  for (int j = 0; j < 4; ++j) v[j] = (i0 + j < NN) ? cnt[i0 + j] : 0;
  int s = v[0] + v[1] + v[2] + v[3];
  sm[t] = s;
  __syncthreads();
  for (int off = 1; off < 256; off <<= 1){
    int add = (t >= off) ? sm[t - off] : 0;
    __syncthreads();
    sm[t] += add;
    __syncthreads();
  }
  int run = sm[t] - s;          // exclusive prefix of this thread
  if (t == 255) bsums[b] = sm[255];
  #pragma unroll
  for (int j = 0; j < 4; ++j){
    if (i0 + j < NN) base[i0 + j] = run;
    run += v[j];
  }
}

__global__ void scan_sums_kernel(int* __restrict__ bsums, int nb){
  __shared__ int sm[256];
  int t = threadIdx.x;
  int v = (t < nb) ? bsums[t] : 0;
  sm[t] = v;
  __syncthreads();
  for (int off = 1; off < 256; off <<= 1){
    int add = (t >= off) ? sm[t - off] : 0;
    __syncthreads();
    sm[t] += add;
    __syncthreads();
  }
  if (t < nb) bsums[t] = sm[t] - v;   // exclusive
}

__global__ __launch_bounds__(256) void scan_add_kernel(int* __restrict__ base,
    const int* __restrict__ bsums, int* __restrict__ cursor){
  int i = blockIdx.x*256 + threadIdx.x;
  if (i >= NN) return;
  int b = base[i] + bsums[i / SCAN_CHUNK];
  base[i] = b;
  cursor[i] = b;
}

// rc[pos] = {row, coef} at pos=cursor[col]++  (single 8B store)
__global__ __launch_bounds__(256) void fill_kernel(const void* __restrict__ ea, long long ea_off,
    const int* __restrict__ ei, long long row_off, long long col_off,
    const float* __restrict__ dinv, const int* __restrict__ flags,
    int* __restrict__ cursor, int2* __restrict__ rc){
  int e = blockIdx.x*256 + threadIdx.x;
  if (e >= NE) return;
  int w64 = flags[0];
  int row = ld_idx(ei, row_off + e, w64);
  int col = ld_idx(ei, col_off + e, w64);
  float w = ldf(ea, ea_off + e, flags[1]);
  int pos = atomicAdd(cursor + col, 1);
  rc[pos] = make_int2(row, __float_as_int(dinv[row] * w * dinv[col]));
}

// one wave per node: agg[n] = sum_j coef[j] * h[rows[j]]
// batched 8-wide: 8 rc loads then 8 independent 512B gathers in flight (MLP)
__global__ __launch_bounds__(256) void aggregate_kernel(
    const void* __restrict__ hbase, long long h_off,
    const int2* __restrict__ rc,
    const int* __restrict__ base, const int* __restrict__ cnt,
    const int* __restrict__ flags, void* __restrict__ agg, int agg_f32){
  int wid = (int)(((long long)blockIdx.x*256 + threadIdx.x) >> 6);
  int l = threadIdx.x & 63;
  if (wid >= NN) return;
  int f32 = flags[1];
  int s = base[wid], e = s + cnt[wid];
  float ax = 0.f, ay = 0.f;

  if (f32){
    const float2* hp = (const float2*)((const float*)hbase + h_off);
    int j = s;
    for (; j + 8 <= e; j += 8){
      int2 v[8];
      #pragma unroll
      for (int k = 0; k < 8; ++k) v[k] = rc[j + k];
      float2 hv[8];
      #pragma unroll
      for (int k = 0; k < 8; ++k) hv[k] = hp[(long long)v[k].x*64 + l];
      #pragma unroll
      for (int k = 0; k < 8; ++k){
        float c = __int_as_float(v[k].y);
        ax += c*hv[k].x; ay += c*hv[k].y;
      }
    }
    if (j < e){   // predicated tail batch: dummy index s, coef forced to 0
      int2 v[8];
      #pragma unroll
      for (int k = 0; k < 8; ++k){
        int jj = (j + k < e) ? (j + k) : s;
        v[k] = rc[jj];
        if (j + k >= e) v[k].y = 0;      // 0x0 == 0.0f
      }
      float2 hv[8];
      #pragma unroll
      for (int k = 0; k < 8; ++k) hv[k] = hp[(long long)v[k].x*64 + l];
      #pragma unroll
      for (int k = 0; k < 8; ++k){
        float c = __int_as_float(v[k].y);
        ax += c*hv[k].x; ay += c*hv[k].y;
      }
    }
  } else {
    const u32* hp = (const u32*)((const u16*)hbase + h_off);
    int j = s;
    for (; j + 8 <= e; j += 8){
      int2 v[8];
      #pragma unroll
      for (int k = 0; k < 8; ++k) v[k] = rc[j + k];
      u32 hv[8];
      #pragma unroll
      for (int k = 0; k < 8; ++k) hv[k] = hp[(long long)v[k].x*64 + l];
      #pragma unroll
      for (int k = 0; k < 8; ++k){
        float c = __int_as_float(v[k].y);
        ax += c*bf2f((u16)(hv[k] & 0xFFFF));
        ay += c*bf2f((u16)(hv[k] >> 16));
      }
    }
    if (j < e){
      int2 v[8];
      #pragma unroll
      for (int k = 0; k < 8; ++k){
        int jj = (j + k < e) ? (j + k) : s;
        v[k] = rc[jj];
        if (j + k >= e) v[k].y = 0;
      }
      u32 hv[8];
      #pragma unroll
      for (int k = 0; k < 8; ++k) hv[k] = hp[(long long)v[k].x*64 + l];
      #pragma unroll
      for (int k = 0; k < 8; ++k){
        float c = __int_as_float(v[k].y);
        ax += c*bf2f((u16)(hv[k] & 0xFFFF));
        ay += c*bf2f((u16)(hv[k] >> 16));
      }
    }
  }
  if (agg_f32) ((float2*)agg)[(long long)wid*64 + l] = make_float2(ax, ay);
  else         ((u32*)agg)[(long long)wid*64 + l] = ((u32)f2bf(ay) << 16) | (u32)f2bf(ax);
}

// out = relu(in @ W^T + bias) via MFMA bf16 with hi/lo split of fp32 inputs.
// in_mode: 0=bf16, 1=f32, 2=follow flags[1].  wbf = bf16 W [128][128] row-major [d][k].
// Block: 256 thr = 4 waves, 64 rows/block (16 rows/wave), full 128 cols (8 col-tiles).
__global__ __launch_bounds__(256) void gemm_mfma_kernel(
    const void* __restrict__ in, int in_mode,
    const u16* __restrict__ wbf,
    const void* __restrict__ bias, long long b_off,
    const int* __restrict__ flags,
    void* __restrict__ outb, long long out_off){
  __shared__ u16 ah[64*DD];   // bf16 hi, XOR-swizzled
  __shared__ u16 al[64*DD];   // bf16 lo (residual), XOR-swizzled
  int t = threadIdx.x;
  int f32 = flags[1];
  int inf32 = (in_mode == 2) ? f32 : in_mode;
  long long rowbase = (long long)blockIdx.x * 64;

  // stage 64x128 input rows -> hi/lo bf16 in LDS (swizzle: u16idx ^= (row&7)<<3)
  #pragma unroll
  for (int it = 0; it < 8; ++it){
    int i = (it*256 + t) * 4;           // element index, multiple of 4
    int r = i >> 7, c = i & 127;
    long long gr = rowbase + r;
    float v0, v1, v2, v3;
    if (gr < NN){
      if (inf32){
        const float4 f = *(const float4*)((const float*)in + gr*DD + c);
        v0 = f.x; v1 = f.y; v2 = f.z; v3 = f.w;
      } else {
        const ushort4 u = *(const ushort4*)((const u16*)in + gr*DD + c);
        v0 = bf2f(u.x); v1 = bf2f(u.y); v2 = bf2f(u.z); v3 = bf2f(u.w);
      }
    } else { v0 = v1 = v2 = v3 = 0.f; }
    u16 h0 = f2bf(v0), h1 = f2bf(v1), h2 = f2bf(v2), h3 = f2bf(v3);
    u16 l0 = f2bf(v0 - bf2f(h0)), l1 = f2bf(v1 - bf2f(h1));
    u16 l2 = f2bf(v2 - bf2f(h2)), l3 = f2bf(v3 - bf2f(h3));
    int idx = (r*DD + c) ^ ((r & 7) << 3);
    *(ushort4*)&ah[idx] = make_ushort4(h0, h1, h2, h3);
    *(ushort4*)&al[idx] = make_ushort4(l0, l1, l2, l3);
  }
  __syncthreads();

  const int w  = t >> 6, l = t & 63;
  const int lr = l & 15, lg = l >> 4;
  const int arow = w*16 + lr;
  f32x4 acc[8];
  #pragma unroll
  for (int j = 0; j < 8; ++j) acc[j] = (f32x4){0.f, 0.f, 0.f, 0.f};

  #pragma unroll
  for (int s = 0; s < 4; ++s){
    const int kb = s*32 + lg*8;
    const int aidx = (arow*DD + kb) ^ ((arow & 7) << 3);
    bf16x8 afh = *(const bf16x8*)&ah[aidx];
    bf16x8 afl = *(const bf16x8*)&al[aidx];
    #pragma unroll
    for (int tt = 0; tt < 8; ++tt){
      bf16x8 bfr = *(const bf16x8*)&wbf[(tt*16 + lr)*DD + kb];
      acc[tt] = __builtin_amdgcn_mfma_f32_16x16x32_bf16(afh, bfr, acc[tt], 0, 0, 0);
      acc[tt] = __builtin_amdgcn_mfma_f32_16x16x32_bf16(afl, bfr, acc[tt], 0, 0, 0);
    }
  }

  // C/D layout: col = lane&15, row = (lane>>4)*4 + reg
  const long long gn0 = rowbase + w*16 + lg*4;
  #pragma unroll
  for (int tt = 0; tt < 8; ++tt){
    const int d = tt*16 + lr;
    const float bv = ldf(bias, b_off + d, f32);
    #pragma unroll
    for (int q = 0; q < 4; ++q){
      long long gn = gn0 + q;
      if (gn < NN){
        float vv = fmaxf(acc[tt][q] + bv, 0.f);
        long long gi = out_off + gn*DD + d;
        if (f32) ((float*)outb)[gi] = vv;
        else     ((u16*)outb)[gi] = f2bf(vv);
      }
    }
  }
}

extern "C" void kernel_launch(void* const* d_in, const int* in_sizes, int n_in,
                              void* d_out, int out_size, void* d_ws, size_t ws_size,
                              hipStream_t stream){
  const void* x      = d_in[0];
  const int*  ei     = (const int*)d_in[1];
  const void* ea     = d_in[2];
  const void* lin_w  = d_in[3];
  const void* lin_b  = d_in[4];
  const void* conv_w = d_in[5];
  const void* conv_b = d_in[6];
  void* out = d_out;

  char* ws = (char*)d_ws;
  size_t o = 0;
  auto alloc = [&](size_t bytes){ void* p = ws + o; o = (o + bytes + 255) & ~(size_t)255; return p; };
  int*   flags  = (int*)  alloc(256);
  u64*   pk     = (u64*)  alloc((size_t)NN*8);   // packed {cnt<<40 | fixpt deg}
  float* dinv   = (float*)alloc((size_t)NN*4);
  int*   cnt    = (int*)  alloc((size_t)NN*4);
  int*   base   = (int*)  alloc((size_t)NN*4);
  int*   cursor = (int*)  alloc((size_t)NN*4);
  int*   bsums  = (int*)  alloc(4096);
  int2*  rc     = (int2*) alloc((size_t)NE*8);
  u16*   wbf    = (u16*)  alloc((size_t)5*DD*DD*2);
  size_t fixed = o;
  int agg_f32 = (ws_size >= fixed + (size_t)NN*DD*4) ? 1 : 0;
  void* agg = alloc((size_t)NN*DD*(agg_f32 ? 4 : 2));

  detect_kernel<<<1, 64, 0, stream>>>(ei, (const u16*)x, flags);
  prep_w_kernel<<<(5*DD*DD + 255)/256, 256, 0, stream>>>(lin_w, conv_w, flags, wbf);

  // layer 0: out[0] = relu(x @ lin_w.T + lin_b)
  gemm_mfma_kernel<<<(NN+63)/64, 256, 0, stream>>>(x, 2, wbf, lin_b, 0, flags, out, 0);

  for (int i = 0; i < 4; ++i){
    long long h_off   = (long long)i*NN*DD;
    long long o_off   = (long long)(i+1)*NN*DD;
    long long row_off = ((long long)i*2 + 0)*NE;
    long long col_off = ((long long)i*2 + 1)*NE;
    long long ea_off  = (long long)i*NE;

    hipMemsetAsync(pk, 0, (size_t)NN*8, stream);
    hist_kernel<<<(NE+255)/256, 256, 0, stream>>>(ea, ea_off, ei, col_off, flags, pk);
    dinv_kernel<<<(NN+255)/256, 256, 0, stream>>>(pk, dinv, cnt);

    scan_block_kernel<<<NBLK, 256, 0, stream>>>(cnt, base, bsums);
    scan_sums_kernel<<<1, 256, 0, stream>>>(bsums, NBLK);
    scan_add_kernel<<<(NN+255)/256, 256, 0, stream>>>(base, bsums, cursor);

    fill_kernel<<<(NE+255)/256, 256, 0, stream>>>(ea, ea_off, ei, row_off, col_off,
                                                  dinv, flags, cursor, rc);

    aggregate_kernel<<<(NN*64 + 255)/256, 256, 0, stream>>>(out, h_off, rc,
                                                            base, cnt, flags, agg, agg_f32);

    gemm_mfma_kernel<<<(NN+63)/64, 256, 0, stream>>>(agg, agg_f32 ? 1 : 0,
                                                     wbf + (size_t)(1+i)*DD*DD,
                                                     conv_b, (long long)i*DD, flags, out, o_off);
  }
}

// Round 3
// 1539.001 us; speedup vs baseline: 1.7349x; 1.0554x over previous
//
#include <hip/hip_runtime.h>

#define NN 100000
#define NE 1600000
#define DD 128
#define SCAN_CHUNK 1024
#define NBLK ((NN + SCAN_CHUNK - 1) / SCAN_CHUNK)   // 98
#define NNP (NBLK * SCAN_CHUNK)                     // 100352 (padded per-layer stride)
#define NTOT (4 * NNP)
#define BPL ((NE + 255) / 256)                      // 6250 blocks per layer

using u16 = unsigned short;
using u32 = unsigned int;
using u64 = unsigned long long;

typedef __bf16 bf16x8 __attribute__((ext_vector_type(8)));
typedef float  f32x4  __attribute__((ext_vector_type(4)));

__device__ __forceinline__ float bf2f(u16 h){ return __uint_as_float(((u32)h) << 16); }
__device__ __forceinline__ u16 f2bf(float f){
  u32 u = __float_as_uint(f);
  u += 0x7FFFu + ((u >> 16) & 1u);   // round-to-nearest-even
  return (u16)(u >> 16);
}
__device__ __forceinline__ int ld_idx(const int* __restrict__ p, long long k, int w64){
  return w64 ? p[2*k] : p[k];
}
__device__ __forceinline__ float ldf(const void* __restrict__ p, long long k, int f32){
  return f32 ? ((const float*)p)[k] : bf2f(((const u16*)p)[k]);
}

// flags[0] = edge_index is int64 layout; flags[1] = float tensors are fp32
__global__ void detect_kernel(const int* __restrict__ ei, const u16* __restrict__ xw,
                              int* __restrict__ flags){
  if (threadIdx.x == 0 && blockIdx.x == 0){
    int all0 = 1;
    for (int k = 1; k < 256; k += 2) all0 &= (ei[k] == 0);
    flags[0] = all0;
    int cnt = 0;
    for (int i = 0; i < 128; ++i){
      u16 w = xw[2*i];
      int e = (w >> 7) & 0xFF;
      cnt += (e >= 100 && e <= 130);
    }
    flags[1] = (cnt < 64);
  }
}

// convert all 5 weight matrices (lin_w, conv_w[0..3]) to bf16 [d][k] row-major
__global__ __launch_bounds__(256) void prep_w_kernel(const void* __restrict__ lin_w,
    const void* __restrict__ conv_w, const int* __restrict__ flags, u16* __restrict__ wbf){
  int i = blockIdx.x*256 + threadIdx.x;
  if (i >= 5*DD*DD) return;
  int f32 = flags[1];
  float v = (i < DD*DD) ? ldf(lin_w, i, f32) : ldf(conv_w, i - DD*DD, f32);
  wbf[i] = f2bf(v);
}

// all 4 layers in one dispatch: pk[lyr][col] += {1<<40 | fixpt(w)}
__global__ __launch_bounds__(256) void hist_all_kernel(const void* __restrict__ ea,
    const int* __restrict__ ei, const int* __restrict__ flags, u64* __restrict__ pk){
  int lyr = blockIdx.x / BPL;
  int e = (blockIdx.x - lyr*BPL)*256 + threadIdx.x;
  if (e >= NE) return;
  long long col_off = ((long long)lyr*2 + 1)*NE;
  long long ea_off  = (long long)lyr*NE;
  int col = ld_idx(ei, col_off + e, flags[0]);
  float w = ldf(ea, ea_off + e, flags[1]);
  u64 v = (1ull << 40) | (u64)(w * 16777216.0f);
  atomicAdd(pk + (size_t)lyr*NNP + col, v);
}

__global__ __launch_bounds__(256) void dinv_all_kernel(const u64* __restrict__ pk,
    float* __restrict__ dinv, int* __restrict__ cnt){
  int n = blockIdx.x*256 + threadIdx.x;
  if (n >= NTOT) return;
  u64 p = pk[n];
  cnt[n] = (int)(p >> 40);
  float d = (float)(p & ((1ull << 40) - 1)) * (1.0f/16777216.0f);
  dinv[n] = (d > 0.f) ? rsqrtf(d) : 0.f;
}

// ---- exclusive scan of cnt[NTOT] into base[NTOT]; layer chunks align (NNP%1024==0) ----
__global__ __launch_bounds__(256) void scan_block_kernel(const int* __restrict__ cnt,
    int* __restrict__ base, int* __restrict__ bsums){
  __shared__ int sm[256];
  int b = blockIdx.x, t = threadIdx.x;
  int i0 = b*SCAN_CHUNK + t*4;
  int v[4];
  #pragma unroll
  for (int j = 0; j < 4; ++j) v[j] = cnt[i0 + j];
  int s = v[0] + v[1] + v[2] + v[3];
  sm[t] = s;
  __syncthreads();
  for (int off = 1; off < 256; off <<= 1){
    int add = (t >= off) ? sm[t - off] : 0;
    __syncthreads();
    sm[t] += add;
    __syncthreads();
  }
  int run = sm[t] - s;          // exclusive prefix of this thread
  if (t == 255) bsums[b] = sm[255];
  #pragma unroll
  for (int j = 0; j < 4; ++j){
    base[i0 + j] = run;
    run += v[j];
  }
}

// per-layer segmented exclusive scan of block sums: grid = 4, nb = NBLK
__global__ void scan_sums_kernel(int* __restrict__ bsums, int nb){
  __shared__ int sm[256];
  int t = threadIdx.x;
  int* bs = bsums + blockIdx.x*nb;
  int v = (t < nb) ? bs[t] : 0;
  sm[t] = v;
  __syncthreads();
  for (int off = 1; off < 256; off <<= 1){
    int add = (t >= off) ? sm[t - off] : 0;
    __syncthreads();
    sm[t] += add;
    __syncthreads();
  }
  if (t < nb) bs[t] = sm[t] - v;   // exclusive
}

__global__ __launch_bounds__(256) void scan_add_kernel(int* __restrict__ base,
    const int* __restrict__ bsums, int* __restrict__ cursor){
  int i = blockIdx.x*256 + threadIdx.x;
  if (i >= NTOT) return;
  int b = base[i] + bsums[i / SCAN_CHUNK];
  base[i] = b;
  cursor[i] = b;
}

// rc[lyr][pos] = {row, coef} at pos=cursor[lyr][col]++  (single 8B store)
__global__ __launch_bounds__(256) void fill_all_kernel(const void* __restrict__ ea,
    const int* __restrict__ ei, const float* __restrict__ dinv,
    const int* __restrict__ flags, int* __restrict__ cursor, int2* __restrict__ rc){
  int lyr = blockIdx.x / BPL;
  int e = (blockIdx.x - lyr*BPL)*256 + threadIdx.x;
  if (e >= NE) return;
  int w64 = flags[0];
  long long row_off = ((long long)lyr*2 + 0)*NE;
  long long col_off = ((long long)lyr*2 + 1)*NE;
  long long ea_off  = (long long)lyr*NE;
  int row = ld_idx(ei, row_off + e, w64);
  int col = ld_idx(ei, col_off + e, w64);
  float w = ldf(ea, ea_off + e, flags[1]);
  const float* dv = dinv + (size_t)lyr*NNP;
  int pos = atomicAdd(cursor + (size_t)lyr*NNP + col, 1);
  rc[(size_t)lyr*NE + pos] = make_int2(row, __float_as_int(dv[row] * w * dv[col]));
}

// out = relu(in @ W^T + bias) via MFMA bf16 hi/lo split (layer 0 only).
__global__ __launch_bounds__(256) void gemm_mfma_kernel(
    const void* __restrict__ in, int in_mode,
    const u16* __restrict__ wbf,
    const void* __restrict__ bias, long long b_off,
    const int* __restrict__ flags,
    void* __restrict__ outb, long long out_off){
  __shared__ u16 ah[64*DD];   // bf16 hi, XOR-swizzled
  __shared__ u16 al[64*DD];   // bf16 lo (residual), XOR-swizzled
  int t = threadIdx.x;
  int f32 = flags[1];
  int inf32 = (in_mode == 2) ? f32 : in_mode;
  long long rowbase = (long long)blockIdx.x * 64;

  #pragma unroll
  for (int it = 0; it < 8; ++it){
    int i = (it*256 + t) * 4;           // element index, multiple of 4
    int r = i >> 7, c = i & 127;
    long long gr = rowbase + r;
    float v0, v1, v2, v3;
    if (gr < NN){
      if (inf32){
        const float4 f = *(const float4*)((const float*)in + gr*DD + c);
        v0 = f.x; v1 = f.y; v2 = f.z; v3 = f.w;
      } else {
        const ushort4 u = *(const ushort4*)((const u16*)in + gr*DD + c);
        v0 = bf2f(u.x); v1 = bf2f(u.y); v2 = bf2f(u.z); v3 = bf2f(u.w);
      }
    } else { v0 = v1 = v2 = v3 = 0.f; }
    u16 h0 = f2bf(v0), h1 = f2bf(v1), h2 = f2bf(v2), h3 = f2bf(v3);
    u16 l0 = f2bf(v0 - bf2f(h0)), l1 = f2bf(v1 - bf2f(h1));
    u16 l2 = f2bf(v2 - bf2f(h2)), l3 = f2bf(v3 - bf2f(h3));
    int idx = (r*DD + c) ^ ((r & 7) << 3);
    *(ushort4*)&ah[idx] = make_ushort4(h0, h1, h2, h3);
    *(ushort4*)&al[idx] = make_ushort4(l0, l1, l2, l3);
  }
  __syncthreads();

  const int w  = t >> 6, l = t & 63;
  const int lr = l & 15, lg = l >> 4;
  const int arow = w*16 + lr;
  f32x4 acc[8];
  #pragma unroll
  for (int j = 0; j < 8; ++j) acc[j] = (f32x4){0.f, 0.f, 0.f, 0.f};

  #pragma unroll
  for (int s = 0; s < 4; ++s){
    const int kb = s*32 + lg*8;
    const int aidx = (arow*DD + kb) ^ ((arow & 7) << 3);
    bf16x8 afh = *(const bf16x8*)&ah[aidx];
    bf16x8 afl = *(const bf16x8*)&al[aidx];
    #pragma unroll
    for (int tt = 0; tt < 8; ++tt){
      bf16x8 bfr = *(const bf16x8*)&wbf[(tt*16 + lr)*DD + kb];
      acc[tt] = __builtin_amdgcn_mfma_f32_16x16x32_bf16(afh, bfr, acc[tt], 0, 0, 0);
      acc[tt] = __builtin_amdgcn_mfma_f32_16x16x32_bf16(afl, bfr, acc[tt], 0, 0, 0);
    }
  }

  // C/D layout: col = lane&15, row = (lane>>4)*4 + reg
  const long long gn0 = rowbase + w*16 + lg*4;
  #pragma unroll
  for (int tt = 0; tt < 8; ++tt){
    const int d = tt*16 + lr;
    const float bv = ldf(bias, b_off + d, f32);
    #pragma unroll
    for (int q = 0; q < 4; ++q){
      long long gn = gn0 + q;
      if (gn < NN){
        float vv = fmaxf(acc[tt][q] + bv, 0.f);
        long long gi = out_off + gn*DD + d;
        if (f32) ((float*)outb)[gi] = vv;
        else     ((u16*)outb)[gi] = f2bf(vv);
      }
    }
  }
}

// Fused: wave w aggregates its own 16 rows (batched-8 gather), writes hi/lo bf16
// straight into the swizzled LDS tile, then the MFMA phase runs as in gemm_mfma.
// Eliminates the agg global round-trip (2 x 51.2 MB per layer).
__global__ __launch_bounds__(256) void agg_gemm_kernel(
    const void* __restrict__ hbase, long long h_off,
    const int2* __restrict__ rc,
    const int* __restrict__ basep, const int* __restrict__ cntp,
    const u16* __restrict__ wbf,
    const void* __restrict__ bias, long long b_off,
    const int* __restrict__ flags,
    void* __restrict__ outb, long long out_off){
  __shared__ u16 ah[64*DD];
  __shared__ u16 al[64*DD];
  int t = threadIdx.x;
  int f32 = flags[1];
  long long rowbase = (long long)blockIdx.x * 64;
  const int w = t >> 6, l = t & 63;

  // phase 1: aggregate rows w*16 .. w*16+15 (lane l holds dims 2l, 2l+1)
  for (int i = 0; i < 16; ++i){
    int r = w*16 + i;
    long long n = rowbase + r;
    float ax = 0.f, ay = 0.f;
    if (n < NN){
      int s = basep[n], e = s + cntp[n];
      if (f32){
        const float2* hp = (const float2*)((const float*)hbase + h_off);
        int j = s;
        for (; j + 8 <= e; j += 8){
          int2 v[8];
          #pragma unroll
          for (int k = 0; k < 8; ++k) v[k] = rc[j + k];
          float2 hv[8];
          #pragma unroll
          for (int k = 0; k < 8; ++k) hv[k] = hp[(long long)v[k].x*64 + l];
          #pragma unroll
          for (int k = 0; k < 8; ++k){
            float c = __int_as_float(v[k].y);
            ax += c*hv[k].x; ay += c*hv[k].y;
          }
        }
        if (j < e){   // predicated tail batch: dummy index s, coef forced to 0
          int2 v[8];
          #pragma unroll
          for (int k = 0; k < 8; ++k){
            int jj = (j + k < e) ? (j + k) : s;
            v[k] = rc[jj];
            if (j + k >= e) v[k].y = 0;
          }
          float2 hv[8];
          #pragma unroll
          for (int k = 0; k < 8; ++k) hv[k] = hp[(long long)v[k].x*64 + l];
          #pragma unroll
          for (int k = 0; k < 8; ++k){
            float c = __int_as_float(v[k].y);
            ax += c*hv[k].x; ay += c*hv[k].y;
          }
        }
      } else {
        const u32* hp = (const u32*)((const u16*)hbase + h_off);
        int j = s;
        for (; j + 8 <= e; j += 8){
          int2 v[8];
          #pragma unroll
          for (int k = 0; k < 8; ++k) v[k] = rc[j + k];
          u32 hv[8];
          #pragma unroll
          for (int k = 0; k < 8; ++k) hv[k] = hp[(long long)v[k].x*64 + l];
          #pragma unroll
          for (int k = 0; k < 8; ++k){
            float c = __int_as_float(v[k].y);
            ax += c*bf2f((u16)(hv[k] & 0xFFFF));
            ay += c*bf2f((u16)(hv[k] >> 16));
          }
        }
        if (j < e){
          int2 v[8];
          #pragma unroll
          for (int k = 0; k < 8; ++k){
            int jj = (j + k < e) ? (j + k) : s;
            v[k] = rc[jj];
            if (j + k >= e) v[k].y = 0;
          }
          u32 hv[8];
          #pragma unroll
          for (int k = 0; k < 8; ++k) hv[k] = hp[(long long)v[k].x*64 + l];
          #pragma unroll
          for (int k = 0; k < 8; ++k){
            float c = __int_as_float(v[k].y);
            ax += c*bf2f((u16)(hv[k] & 0xFFFF));
            ay += c*bf2f((u16)(hv[k] >> 16));
          }
        }
      }
    }
    u16 h0 = f2bf(ax), h1 = f2bf(ay);
    u16 l0 = f2bf(ax - bf2f(h0)), l1 = f2bf(ay - bf2f(h1));
    int idx = (r*DD + 2*l) ^ ((r & 7) << 3);   // XOR touches bits>=3: u32 stays aligned
    *(u32*)&ah[idx] = (u32)h0 | ((u32)h1 << 16);
    *(u32*)&al[idx] = (u32)l0 | ((u32)l1 << 16);
  }
  __syncthreads();

  // phase 2: MFMA (each wave consumes exactly the rows it aggregated)
  const int lr = l & 15, lg = l >> 4;
  const int arow = w*16 + lr;
  f32x4 acc[8];
  #pragma unroll
  for (int j = 0; j < 8; ++j) acc[j] = (f32x4){0.f, 0.f, 0.f, 0.f};

  #pragma unroll
  for (int s = 0; s < 4; ++s){
    const int kb = s*32 + lg*8;
    const int aidx = (arow*DD + kb) ^ ((arow & 7) << 3);
    bf16x8 afh = *(const bf16x8*)&ah[aidx];
    bf16x8 afl = *(const bf16x8*)&al[aidx];
    #pragma unroll
    for (int tt = 0; tt < 8; ++tt){
      bf16x8 bfr = *(const bf16x8*)&wbf[(tt*16 + lr)*DD + kb];
      acc[tt] = __builtin_amdgcn_mfma_f32_16x16x32_bf16(afh, bfr, acc[tt], 0, 0, 0);
      acc[tt] = __builtin_amdgcn_mfma_f32_16x16x32_bf16(afl, bfr, acc[tt], 0, 0, 0);
    }
  }

  const long long gn0 = rowbase + w*16 + lg*4;
  #pragma unroll
  for (int tt = 0; tt < 8; ++tt){
    const int d = tt*16 + lr;
    const float bv = ldf(bias, b_off + d, f32);
    #pragma unroll
    for (int q = 0; q < 4; ++q){
      long long gn = gn0 + q;
      if (gn < NN){
        float vv = fmaxf(acc[tt][q] + bv, 0.f);
        long long gi = out_off + gn*DD + d;
        if (f32) ((float*)outb)[gi] = vv;
        else     ((u16*)outb)[gi] = f2bf(vv);
      }
    }
  }
}

extern "C" void kernel_launch(void* const* d_in, const int* in_sizes, int n_in,
                              void* d_out, int out_size, void* d_ws, size_t ws_size,
                              hipStream_t stream){
  const void* x      = d_in[0];
  const int*  ei     = (const int*)d_in[1];
  const void* ea     = d_in[2];
  const void* lin_w  = d_in[3];
  const void* lin_b  = d_in[4];
  const void* conv_w = d_in[5];
  const void* conv_b = d_in[6];
  void* out = d_out;

  char* ws = (char*)d_ws;
  size_t o = 0;
  auto alloc = [&](size_t bytes){ void* p = ws + o; o = (o + bytes + 255) & ~(size_t)255; return p; };
  int*   flags  = (int*)  alloc(256);
  u64*   pk     = (u64*)  alloc((size_t)NTOT*8);   // packed {cnt<<40 | fixpt deg}, [4][NNP]
  float* dinv   = (float*)alloc((size_t)NTOT*4);
  int*   cnt    = (int*)  alloc((size_t)NTOT*4);
  int*   base   = (int*)  alloc((size_t)NTOT*4);
  int*   cursor = (int*)  alloc((size_t)NTOT*4);
  int*   bsums  = (int*)  alloc((size_t)4*NBLK*4 + 256);
  int2*  rc     = (int2*) alloc((size_t)4*NE*8);   // [4][NE]
  u16*   wbf    = (u16*)  alloc((size_t)5*DD*DD*2);

  detect_kernel<<<1, 64, 0, stream>>>(ei, (const u16*)x, flags);
  prep_w_kernel<<<(5*DD*DD + 255)/256, 256, 0, stream>>>(lin_w, conv_w, flags, wbf);

  // ---- CSR build for all 4 layers up front (h-independent) ----
  hipMemsetAsync(pk, 0, (size_t)NTOT*8, stream);
  hist_all_kernel<<<4*BPL, 256, 0, stream>>>(ea, ei, flags, pk);
  dinv_all_kernel<<<(NTOT+255)/256, 256, 0, stream>>>(pk, dinv, cnt);
  scan_block_kernel<<<4*NBLK, 256, 0, stream>>>(cnt, base, bsums);
  scan_sums_kernel<<<4, 256, 0, stream>>>(bsums, NBLK);
  scan_add_kernel<<<(NTOT+255)/256, 256, 0, stream>>>(base, bsums, cursor);
  fill_all_kernel<<<4*BPL, 256, 0, stream>>>(ea, ei, dinv, flags, cursor, rc);

  // layer 0: out[0] = relu(x @ lin_w.T + lin_b)
  gemm_mfma_kernel<<<(NN+63)/64, 256, 0, stream>>>(x, 2, wbf, lin_b, 0, flags, out, 0);

  // layers 1..4: fused aggregate + GEMM
  for (int i = 0; i < 4; ++i){
    long long h_off = (long long)i*NN*DD;
    long long o_off = (long long)(i+1)*NN*DD;
    agg_gemm_kernel<<<(NN+63)/64, 256, 0, stream>>>(out, h_off,
                                                    rc + (size_t)i*NE,
                                                    base + (size_t)i*NNP,
                                                    cnt  + (size_t)i*NNP,
                                                    wbf + (size_t)(1+i)*DD*DD,
                                                    conv_b, (long long)i*DD,
                                                    flags, out, o_off);
  }
}